// Round 9
// baseline (62.144 us; speedup 1.0000x reference)
//
#include <hip/hip_runtime.h>
#include <hip/hip_bf16.h>

// RedistributionNetwork: 128 sequential tridiagonal layers on [256,1024] f32 state.
// ROUND 9 = ROUND 8 kernels byte-identical; propagate9 launched 3x (idempotent)
// as an in-band timing probe: P = (dur - 29.5)/2, G = 29.5 - P - ovh.

#define NXL 128   // layers
#define NYP 1024  // state width
#define NB  256   // batch
#define NQ  32    // quads
#define SL  128   // output rows per compose block
#define HR  136   // gathered rows per layer per block (SL + 8 halo)

// 4B-aligned float4 (band rows are only dword-aligned)
struct __attribute__((packed, aligned(4))) f4u { float x, y, z, w; };

// ---------------- kernel A: fused gather + compose (identical to round 8) ----------------
__global__ __launch_bounds__(256) void gather_compose(const float* __restrict__ W,
                                                      __hip_bfloat16* __restrict__ band9) {
    __shared__ float ta[4][3][HR];   // [layer][a,b,c][local row]
    const int blk = blockIdx.x;      // 0..255
    const int q   = blk >> 3;
    const int s   = blk & 7;
    const int i0  = s * SL;          // output rows [i0, i0+SL)
    const int tid = threadIdx.x;

#pragma unroll
    for (int g = tid; g < 4 * HR; g += 256) {
        int ly = g / HR;             // 0..3
        int rr = g - ly * HR;        // 0..135
        int i  = i0 - 4 + rr;        // global row, may be out of range
        float a = 0.0f, b = 0.0f, c = 0.0f;
        if ((unsigned)i < NYP) {
            size_t base = ((size_t)(4 * q + ly) << 20) + (size_t)i * (NYP + 1);
            const float* lp = W + base + ((i == 0) ? 0 : (i == NYP - 1) ? -3 : -1);
            f4u v = *reinterpret_cast<const f4u*>(lp);
            if (i == 0)            { a = 0.0f; b = v.x; c = v.y; }
            else if (i == NYP - 1) { a = v.z;  b = v.w; c = 0.0f; }
            else                   { a = v.x;  b = v.y; c = v.z; }
        }
        ta[ly][0][rr] = a;
        ta[ly][1][rr] = b;
        ta[ly][2][rr] = c;
    }
    __syncthreads();

    if (tid < SL) {
        const int i  = i0 + tid;     // output row
        const int li = tid + 4;      // LDS index of column i
        float p[11], r[11];
#pragma unroll
        for (int k = 0; k < 11; ++k) { p[k] = 0.0f; r[k] = 0.0f; }
        p[4] = ta[3][0][li]; p[5] = ta[3][1][li]; p[6] = ta[3][2][li];  // e_i^T W3

#pragma unroll
        for (int d = -2; d <= 2; ++d)
            r[d + 5] = fmaf(p[d + 6], ta[2][0][li + d + 1],
                       fmaf(p[d + 5], ta[2][1][li + d],
                            p[d + 4] * ta[2][2][li + d - 1]));
#pragma unroll
        for (int k = 0; k < 11; ++k) p[k] = r[k];

#pragma unroll
        for (int d = -3; d <= 3; ++d)
            r[d + 5] = fmaf(p[d + 6], ta[1][0][li + d + 1],
                       fmaf(p[d + 5], ta[1][1][li + d],
                            p[d + 4] * ta[1][2][li + d - 1]));
#pragma unroll
        for (int k = 0; k < 11; ++k) p[k] = r[k];

#pragma unroll
        for (int d = -4; d <= 4; ++d)
            r[d + 5] = fmaf(p[d + 6], ta[0][0][li + d + 1],
                       fmaf(p[d + 5], ta[0][1][li + d],
                            p[d + 4] * ta[0][2][li + d - 1]));

        __hip_bfloat16* dst = band9 + (size_t)q * 9 * NYP + i;
#pragma unroll
        for (int d = 0; d < 9; ++d)
            dst[d * NYP] = __float2bfloat16(r[d + 1]);
    }
}

// ---------------- kernel B: 9-diagonal propagation (identical to round 8) ----------------
struct B9u { uint2 d[9]; };

__device__ __forceinline__ void load9(const __hip_bfloat16* __restrict__ band9,
                                      int q, int r0, B9u& w) {
    const __hip_bfloat16* base = band9 + (size_t)q * 9 * NYP + r0;
#pragma unroll
    for (int d = 0; d < 9; ++d)
        w.d[d] = *reinterpret_cast<const uint2*>(base + d * NYP);
}

__device__ __forceinline__ float blo(unsigned u) { return __uint_as_float(u << 16); }
__device__ __forceinline__ float bhi(unsigned u) { return __uint_as_float(u & 0xffff0000u); }

__device__ __forceinline__ float wc(const B9u& w, int d, int j) {
    unsigned u = (j < 2) ? w.d[d].x : w.d[d].y;
    return (j & 1) ? bhi(u) : blo(u);
}

__device__ __forceinline__ void step9(float (&h)[4], const B9u& w,
                                      float (&hLds)[4], float (&hRds)[4],
                                      float (*nxt)[2][4], int wv, int lane) {
    float hl[4], hr[4];
#pragma unroll
    for (int j = 0; j < 4; ++j) {
        float su = __shfl_up(h[j], 1);
        float sd = __shfl_down(h[j], 1);
        hl[j] = (lane == 0)  ? hLds[j] : su;
        hr[j] = (lane == 63) ? hRds[j] : sd;
    }
    float n[4];
#pragma unroll
    for (int j = 0; j < 4; ++j) {
        float acc = 0.0f;
#pragma unroll
        for (int d = 0; d < 9; ++d)
            if (j + d >= 4 && j + d <= 7) acc = fmaf(wc(w, d, j), h[j + d - 4], acc);
#pragma unroll
        for (int d = 0; d < 9; ++d)
            if (j + d < 4) acc = fmaf(wc(w, d, j), hl[j + d], acc);
#pragma unroll
        for (int d = 0; d < 9; ++d)
            if (j + d > 7) acc = fmaf(wc(w, d, j), hr[j + d - 8], acc);
        n[j] = acc;
    }
#pragma unroll
    for (int j = 0; j < 4; ++j) h[j] = n[j];
    if (lane == 0) {
#pragma unroll
        for (int j = 0; j < 4; ++j) nxt[wv][0][j] = h[j];
    }
    if (lane == 63) {
#pragma unroll
        for (int j = 0; j < 4; ++j) nxt[wv][1][j] = h[j];
    }
    asm volatile("s_waitcnt lgkmcnt(0)" ::: "memory");
    __builtin_amdgcn_s_barrier();
#pragma unroll
    for (int j = 0; j < 4; ++j) {
        hLds[j] = nxt[(wv + 3) & 3][1][j];
        hRds[j] = nxt[(wv + 1) & 3][0][j];
    }
}

__global__ __launch_bounds__(256) void propagate9(const float* __restrict__ x,
                                                  const __hip_bfloat16* __restrict__ band9,
                                                  float* __restrict__ out) {
    __shared__ float hal[2][4][2][4];
    const int b    = blockIdx.x;
    const int tid  = threadIdx.x;
    const int wv   = tid >> 6;
    const int lane = tid & 63;
    const int r0   = tid * 4;

    float h[4];
    {
        float4 v = *reinterpret_cast<const float4*>(x + (size_t)b * NYP + r0);
        h[0] = v.x; h[1] = v.y; h[2] = v.z; h[3] = v.w;
    }

    B9u WA, WB;
    load9(band9, 0, r0, WA);

    if (lane == 0) {
#pragma unroll
        for (int j = 0; j < 4; ++j) hal[0][wv][0][j] = h[j];
    }
    if (lane == 63) {
#pragma unroll
        for (int j = 0; j < 4; ++j) hal[0][wv][1][j] = h[j];
    }
    asm volatile("s_waitcnt lgkmcnt(0)" ::: "memory");
    __builtin_amdgcn_s_barrier();
    float hLds[4], hRds[4];
#pragma unroll
    for (int j = 0; j < 4; ++j) {
        hLds[j] = hal[0][(wv + 3) & 3][1][j];
        hRds[j] = hal[0][(wv + 1) & 3][0][j];
    }

#pragma unroll 1
    for (int s = 0; s < NQ; s += 2) {
        load9(band9, (s + 1 < NQ) ? s + 1 : NQ - 1, r0, WB);
        step9(h, WA, hLds, hRds, hal[1], wv, lane);
        load9(band9, (s + 2 < NQ) ? s + 2 : NQ - 1, r0, WA);
        step9(h, WB, hLds, hRds, hal[0], wv, lane);
    }

    *reinterpret_cast<float4*>(out + (size_t)b * NYP + r0) =
        make_float4(h[0], h[1], h[2], h[3]);
}

// ---------------- fallback: direct tridiag sweep from W (ws too small) ----------------
__device__ __forceinline__ float gAw(const float* __restrict__ Wl, int r) {
    return (r >= 1 && r < NYP) ? Wl[(size_t)r * NYP + (r - 1)] : 0.0f;
}
__device__ __forceinline__ float gBw(const float* __restrict__ Wl, int r) {
    return ((unsigned)r < NYP) ? Wl[(size_t)r * NYP + r] : 0.0f;
}
__device__ __forceinline__ float gCw(const float* __restrict__ Wl, int r) {
    return (r >= 0 && r < NYP - 1) ? Wl[(size_t)r * NYP + (r + 1)] : 0.0f;
}

struct W4 { float4 a, b, c; };

__device__ __forceinline__ void lds_barrier() {
    asm volatile("s_waitcnt lgkmcnt(0)" ::: "memory");
    __builtin_amdgcn_s_barrier();
}

__device__ __forceinline__ void layer_step(float (&h)[4], const W4& w,
                                           float (*cur)[2], float (*nxt)[2],
                                           int wv, int lane) {
    float ldsL = cur[(wv + 3) & 3][1];
    float ldsR = cur[(wv + 1) & 3][0];
    float left  = __shfl_up(h[3], 1);
    float right = __shfl_down(h[0], 1);
    if (lane == 0)  left  = ldsL;
    if (lane == 63) right = ldsR;
    float n0 = fmaf(w.a.x, left, fmaf(w.b.x, h[0], w.c.x * h[1]));
    float n1 = fmaf(w.a.y, h[0], fmaf(w.b.y, h[1], w.c.y * h[2]));
    float n2 = fmaf(w.a.z, h[1], fmaf(w.b.z, h[2], w.c.z * h[3]));
    float n3 = fmaf(w.a.w, h[2], fmaf(w.b.w, h[3], w.c.w * right));
    h[0] = n0; h[1] = n1; h[2] = n2; h[3] = n3;
    if (lane == 0)  nxt[wv][0] = h[0];
    if (lane == 63) nxt[wv][1] = h[3];
    lds_barrier();
}

__global__ __launch_bounds__(256) void propagate_direct(const float* __restrict__ x,
                                                        const float* __restrict__ W,
                                                        float* __restrict__ out) {
    __shared__ float hal[2][4][2];
    const int b    = blockIdx.x;
    const int tid  = threadIdx.x;
    const int wv   = tid >> 6;
    const int lane = tid & 63;
    const int r0   = tid * 4;

    float h[4];
    {
        float4 v = *reinterpret_cast<const float4*>(x + (size_t)b * NYP + r0);
        h[0] = v.x; h[1] = v.y; h[2] = v.z; h[3] = v.w;
    }

    if (lane == 0)  hal[0][wv][0] = h[0];
    if (lane == 63) hal[0][wv][1] = h[3];
    lds_barrier();

#pragma unroll 1
    for (int l = 0; l < NXL; ++l) {
        W4 w;
        float t0[4], t1[4], t2[4];
        const float* Wl = W + ((size_t)l << 20);
#pragma unroll
        for (int k = 0; k < 4; ++k) {
            int i = r0 + k;
            t0[k] = gAw(Wl, i); t1[k] = gBw(Wl, i); t2[k] = gCw(Wl, i);
        }
        w.a = make_float4(t0[0], t0[1], t0[2], t0[3]);
        w.b = make_float4(t1[0], t1[1], t1[2], t1[3]);
        w.c = make_float4(t2[0], t2[1], t2[2], t2[3]);
        if (l & 1) layer_step(h, w, hal[1], hal[0], wv, lane);
        else       layer_step(h, w, hal[0], hal[1], wv, lane);
    }

    *reinterpret_cast<float4*>(out + (size_t)b * NYP + r0) =
        make_float4(h[0], h[1], h[2], h[3]);
}

extern "C" void kernel_launch(void* const* d_in, const int* in_sizes, int n_in,
                              void* d_out, int out_size, void* d_ws, size_t ws_size,
                              hipStream_t stream) {
    const float* x = (const float*)d_in[0];   // [256,1024] f32
    const float* W = (const float*)d_in[1];   // [128,1024,1024] f32
    float* out = (float*)d_out;               // [256,1024] f32

    const size_t band9Bytes = (size_t)NQ * 9 * NYP * sizeof(__hip_bfloat16);  // 576 KB
    if (ws_size >= band9Bytes) {
        __hip_bfloat16* band9 = (__hip_bfloat16*)d_ws;
        gather_compose<<<NQ * 8, 256, 0, stream>>>(W, band9);
        // TIMING PROBE: propagate9 is idempotent (reads x, band9; deterministic
        // out). Launch 3x so the bench delta vs round 8 isolates P = delta/2.
        propagate9<<<NB, 256, 0, stream>>>(x, band9, out);
        propagate9<<<NB, 256, 0, stream>>>(x, band9, out);
        propagate9<<<NB, 256, 0, stream>>>(x, band9, out);
    } else {
        propagate_direct<<<NB, 256, 0, stream>>>(x, W, out);
    }
}

// Round 10
// 53.867 us; speedup vs baseline: 1.1537x; 1.1537x over previous
//
#include <hip/hip_runtime.h>
#include <hip/hip_bf16.h>

// RedistributionNetwork: 128 sequential tridiagonal layers on [256,1024] f32 state.
// Pipeline (2 kernels):
//  (A) gather_compose (identical to round 8): gather 4 layers' tridiag rows into
//      LDS (one dwordx4 per row), compose the 4-layer product's 9 diagonals,
//      write bf16 band9[32][9][1024].
//  (B) propagate9w: WAVE-AUTONOMOUS propagation. One 64-lane wave per batch
//      element owns all 1024 rows (16 rows/lane). Halo = 8 register shuffles.
//      NO LDS, NO barriers (round-9 probe showed the 4-wave barriered version
//      cost 1220 cy/step of exposed sync+LDS latency).

#define NXL 128   // layers
#define NYP 1024  // state width
#define NB  256   // batch
#define NQ  32    // quads
#define SL  128   // output rows per compose block
#define HR  136   // gathered rows per layer per block (SL + 8 halo)

// 4B-aligned float4 (band rows are only dword-aligned)
struct __attribute__((packed, aligned(4))) f4u { float x, y, z, w; };

// ---------------- kernel A: fused gather + compose (identical to round 8) ----------------
__global__ __launch_bounds__(256) void gather_compose(const float* __restrict__ W,
                                                      __hip_bfloat16* __restrict__ band9) {
    __shared__ float ta[4][3][HR];   // [layer][a,b,c][local row]
    const int blk = blockIdx.x;      // 0..255
    const int q   = blk >> 3;
    const int s   = blk & 7;
    const int i0  = s * SL;          // output rows [i0, i0+SL)
    const int tid = threadIdx.x;

#pragma unroll
    for (int g = tid; g < 4 * HR; g += 256) {
        int ly = g / HR;             // 0..3
        int rr = g - ly * HR;        // 0..135
        int i  = i0 - 4 + rr;        // global row, may be out of range
        float a = 0.0f, b = 0.0f, c = 0.0f;
        if ((unsigned)i < NYP) {
            size_t base = ((size_t)(4 * q + ly) << 20) + (size_t)i * (NYP + 1);
            const float* lp = W + base + ((i == 0) ? 0 : (i == NYP - 1) ? -3 : -1);
            f4u v = *reinterpret_cast<const f4u*>(lp);
            if (i == 0)            { a = 0.0f; b = v.x; c = v.y; }
            else if (i == NYP - 1) { a = v.z;  b = v.w; c = 0.0f; }
            else                   { a = v.x;  b = v.y; c = v.z; }
        }
        ta[ly][0][rr] = a;
        ta[ly][1][rr] = b;
        ta[ly][2][rr] = c;
    }
    __syncthreads();

    if (tid < SL) {
        const int i  = i0 + tid;     // output row
        const int li = tid + 4;      // LDS index of column i
        float p[11], r[11];
#pragma unroll
        for (int k = 0; k < 11; ++k) { p[k] = 0.0f; r[k] = 0.0f; }
        p[4] = ta[3][0][li]; p[5] = ta[3][1][li]; p[6] = ta[3][2][li];  // e_i^T W3

#pragma unroll
        for (int d = -2; d <= 2; ++d)
            r[d + 5] = fmaf(p[d + 6], ta[2][0][li + d + 1],
                       fmaf(p[d + 5], ta[2][1][li + d],
                            p[d + 4] * ta[2][2][li + d - 1]));
#pragma unroll
        for (int k = 0; k < 11; ++k) p[k] = r[k];

#pragma unroll
        for (int d = -3; d <= 3; ++d)
            r[d + 5] = fmaf(p[d + 6], ta[1][0][li + d + 1],
                       fmaf(p[d + 5], ta[1][1][li + d],
                            p[d + 4] * ta[1][2][li + d - 1]));
#pragma unroll
        for (int k = 0; k < 11; ++k) p[k] = r[k];

#pragma unroll
        for (int d = -4; d <= 4; ++d)
            r[d + 5] = fmaf(p[d + 6], ta[0][0][li + d + 1],
                       fmaf(p[d + 5], ta[0][1][li + d],
                            p[d + 4] * ta[0][2][li + d - 1]));

        __hip_bfloat16* dst = band9 + (size_t)q * 9 * NYP + i;
#pragma unroll
        for (int d = 0; d < 9; ++d)
            dst[d * NYP] = __float2bfloat16(r[d + 1]);
    }
}

// ---------------- kernel B: wave-autonomous 9-diagonal propagation ----------------
__device__ __forceinline__ float blo(unsigned u) { return __uint_as_float(u << 16); }
__device__ __forceinline__ float bhi(unsigned u) { return __uint_as_float(u & 0xffff0000u); }

struct QW { uint4 u[18]; };   // 9 diagonals x 16 rows bf16 (constant-index only)

__device__ __forceinline__ void loadQ(const __hip_bfloat16* __restrict__ band9,
                                      int q, int r0, QW& w) {
    const __hip_bfloat16* base = band9 + (size_t)q * 9 * NYP + r0;
#pragma unroll
    for (int d = 0; d < 9; ++d) {
        w.u[2 * d]     = *reinterpret_cast<const uint4*>(base + d * NYP);
        w.u[2 * d + 1] = *reinterpret_cast<const uint4*>(base + d * NYP + 8);
    }
}

__device__ __forceinline__ float getw(const QW& w, int d, int j) {
    // d, j compile-time constants at every call site
    const uint4& u = w.u[2 * d + (j >> 3)];
    int k = (j >> 1) & 3;
    unsigned v = (k == 0) ? u.x : (k == 1) ? u.y : (k == 2) ? u.z : u.w;
    return (j & 1) ? bhi(v) : blo(v);
}

__device__ __forceinline__ void stepW(float (&h)[16], const QW& w) {
    // halo: 4 rows each side from neighbor lanes; lane-0/63 garbage is
    // annihilated by the exact-0 out-of-matrix coefficients in band9
    float lh[4], rh[4];
#pragma unroll
    for (int t = 0; t < 4; ++t) {
        lh[t] = __shfl_up(h[12 + t], 1);    // prev lane's rows r0-4..r0-1
        rh[t] = __shfl_down(h[t], 1);       // next lane's rows r0+16..r0+19
    }
    float n[16];
#pragma unroll
    for (int j = 0; j < 16; ++j) {
        float acc = 0.0f;
#pragma unroll
        for (int d = 0; d < 9; ++d) {
            int e = j + d - 4;
            float hv = (e < 0) ? lh[e + 4] : (e > 15) ? rh[e - 16] : h[e];
            acc = fmaf(getw(w, d, j), hv, acc);
        }
        n[j] = acc;
    }
#pragma unroll
    for (int j = 0; j < 16; ++j) h[j] = n[j];
}

__global__ __launch_bounds__(64) void propagate9w(const float* __restrict__ x,
                                                  const __hip_bfloat16* __restrict__ band9,
                                                  float* __restrict__ out) {
    const int b    = blockIdx.x;
    const int lane = threadIdx.x & 63;
    const int r0   = lane * 16;

    float h[16];
    const float4* xb = reinterpret_cast<const float4*>(x + (size_t)b * NYP + r0);
#pragma unroll
    for (int t = 0; t < 4; ++t) {
        float4 v = xb[t];
        h[4 * t + 0] = v.x; h[4 * t + 1] = v.y;
        h[4 * t + 2] = v.z; h[4 * t + 3] = v.w;
    }

    QW QA, QB;
    loadQ(band9, 0, r0, QA);

#pragma unroll 1
    for (int s = 0; s < NQ; s += 2) {
        loadQ(band9, (s + 1 < NQ) ? s + 1 : NQ - 1, r0, QB);
        stepW(h, QA);
        loadQ(band9, (s + 2 < NQ) ? s + 2 : NQ - 1, r0, QA);
        stepW(h, QB);
    }

    float4* ob = reinterpret_cast<float4*>(out + (size_t)b * NYP + r0);
#pragma unroll
    for (int t = 0; t < 4; ++t)
        ob[t] = make_float4(h[4 * t + 0], h[4 * t + 1], h[4 * t + 2], h[4 * t + 3]);
}

// ---------------- fallback: direct tridiag sweep from W (ws too small) ----------------
__device__ __forceinline__ float gAw(const float* __restrict__ Wl, int r) {
    return (r >= 1 && r < NYP) ? Wl[(size_t)r * NYP + (r - 1)] : 0.0f;
}
__device__ __forceinline__ float gBw(const float* __restrict__ Wl, int r) {
    return ((unsigned)r < NYP) ? Wl[(size_t)r * NYP + r] : 0.0f;
}
__device__ __forceinline__ float gCw(const float* __restrict__ Wl, int r) {
    return (r >= 0 && r < NYP - 1) ? Wl[(size_t)r * NYP + (r + 1)] : 0.0f;
}

__global__ __launch_bounds__(64) void propagate_direct(const float* __restrict__ x,
                                                       const float* __restrict__ W,
                                                       float* __restrict__ out) {
    const int b    = blockIdx.x;
    const int lane = threadIdx.x & 63;
    const int r0   = lane * 16;

    float h[16];
    const float4* xb = reinterpret_cast<const float4*>(x + (size_t)b * NYP + r0);
#pragma unroll
    for (int t = 0; t < 4; ++t) {
        float4 v = xb[t];
        h[4 * t + 0] = v.x; h[4 * t + 1] = v.y;
        h[4 * t + 2] = v.z; h[4 * t + 3] = v.w;
    }

#pragma unroll 1
    for (int l = 0; l < NXL; ++l) {
        const float* Wl = W + ((size_t)l << 20);
        float a[16], bb[16], c[16];
#pragma unroll
        for (int k = 0; k < 16; ++k) {
            int i = r0 + k;
            a[k] = gAw(Wl, i); bb[k] = gBw(Wl, i); c[k] = gCw(Wl, i);
        }
        float left  = __shfl_up(h[15], 1);
        float right = __shfl_down(h[0], 1);
        float carry = left;
        float n[16];
#pragma unroll
        for (int j = 0; j < 16; ++j) {
            float hp = (j == 15) ? right : h[j + 1];
            n[j] = fmaf(a[j], carry, fmaf(bb[j], h[j], c[j] * hp));
            carry = h[j];
        }
#pragma unroll
        for (int j = 0; j < 16; ++j) h[j] = n[j];
    }

    float4* ob = reinterpret_cast<float4*>(out + (size_t)b * NYP + r0);
#pragma unroll
    for (int t = 0; t < 4; ++t)
        ob[t] = make_float4(h[4 * t + 0], h[4 * t + 1], h[4 * t + 2], h[4 * t + 3]);
}

extern "C" void kernel_launch(void* const* d_in, const int* in_sizes, int n_in,
                              void* d_out, int out_size, void* d_ws, size_t ws_size,
                              hipStream_t stream) {
    const float* x = (const float*)d_in[0];   // [256,1024] f32
    const float* W = (const float*)d_in[1];   // [128,1024,1024] f32
    float* out = (float*)d_out;               // [256,1024] f32

    const size_t band9Bytes = (size_t)NQ * 9 * NYP * sizeof(__hip_bfloat16);  // 576 KB
    if (ws_size >= band9Bytes) {
        __hip_bfloat16* band9 = (__hip_bfloat16*)d_ws;
        gather_compose<<<NQ * 8, 256, 0, stream>>>(W, band9);
        propagate9w<<<NB, 64, 0, stream>>>(x, band9, out);
    } else {
        propagate_direct<<<NB, 64, 0, stream>>>(x, W, out);
    }
}

// Round 11
// 27.486 us; speedup vs baseline: 2.2610x; 1.9598x over previous
//
#include <hip/hip_runtime.h>
#include <hip/hip_bf16.h>

// RedistributionNetwork: 128 sequential tridiagonal layers on [256,1024] f32 state.
// Pipeline (2 kernels):
//  (A) gather_compose (identical to rounds 8-10): one dwordx4 per (layer,row),
//      compose 4-layer products -> bf16 band9[32][9][1024].
//  (B) propagate9x: 32 nine-diagonal steps. 512 threads = 8 waves = 2 waves/SIMD
//      (TLP hides barrier/LDS/shuffle latency - R8's 4-wave version had 1/SIMD
//      and measured 1220 cy/step vs ~300 issue; R10's 1-wave was worse still).
//      Lane owns 2 rows; halo via 8 shuffles + parity-LDS patches at wave edges.

#define NXL 128   // layers
#define NYP 1024  // state width
#define NB  256   // batch
#define NQ  32    // quads
#define SL  128   // output rows per compose block
#define HR  136   // gathered rows per layer per block (SL + 8 halo)

struct __attribute__((packed, aligned(4))) f4u { float x, y, z, w; };

// ---------------- kernel A: fused gather + compose (identical to round 8) ----------------
__global__ __launch_bounds__(256) void gather_compose(const float* __restrict__ W,
                                                      __hip_bfloat16* __restrict__ band9) {
    __shared__ float ta[4][3][HR];   // [layer][a,b,c][local row]
    const int blk = blockIdx.x;      // 0..255
    const int q   = blk >> 3;
    const int s   = blk & 7;
    const int i0  = s * SL;
    const int tid = threadIdx.x;

#pragma unroll
    for (int g = tid; g < 4 * HR; g += 256) {
        int ly = g / HR;
        int rr = g - ly * HR;
        int i  = i0 - 4 + rr;
        float a = 0.0f, b = 0.0f, c = 0.0f;
        if ((unsigned)i < NYP) {
            size_t base = ((size_t)(4 * q + ly) << 20) + (size_t)i * (NYP + 1);
            const float* lp = W + base + ((i == 0) ? 0 : (i == NYP - 1) ? -3 : -1);
            f4u v = *reinterpret_cast<const f4u*>(lp);
            if (i == 0)            { a = 0.0f; b = v.x; c = v.y; }
            else if (i == NYP - 1) { a = v.z;  b = v.w; c = 0.0f; }
            else                   { a = v.x;  b = v.y; c = v.z; }
        }
        ta[ly][0][rr] = a;
        ta[ly][1][rr] = b;
        ta[ly][2][rr] = c;
    }
    __syncthreads();

    if (tid < SL) {
        const int i  = i0 + tid;
        const int li = tid + 4;
        float p[11], r[11];
#pragma unroll
        for (int k = 0; k < 11; ++k) { p[k] = 0.0f; r[k] = 0.0f; }
        p[4] = ta[3][0][li]; p[5] = ta[3][1][li]; p[6] = ta[3][2][li];

#pragma unroll
        for (int d = -2; d <= 2; ++d)
            r[d + 5] = fmaf(p[d + 6], ta[2][0][li + d + 1],
                       fmaf(p[d + 5], ta[2][1][li + d],
                            p[d + 4] * ta[2][2][li + d - 1]));
#pragma unroll
        for (int k = 0; k < 11; ++k) p[k] = r[k];

#pragma unroll
        for (int d = -3; d <= 3; ++d)
            r[d + 5] = fmaf(p[d + 6], ta[1][0][li + d + 1],
                       fmaf(p[d + 5], ta[1][1][li + d],
                            p[d + 4] * ta[1][2][li + d - 1]));
#pragma unroll
        for (int k = 0; k < 11; ++k) p[k] = r[k];

#pragma unroll
        for (int d = -4; d <= 4; ++d)
            r[d + 5] = fmaf(p[d + 6], ta[0][0][li + d + 1],
                       fmaf(p[d + 5], ta[0][1][li + d],
                            p[d + 4] * ta[0][2][li + d - 1]));

        __hip_bfloat16* dst = band9 + (size_t)q * 9 * NYP + i;
#pragma unroll
        for (int d = 0; d < 9; ++d)
            dst[d * NYP] = __float2bfloat16(r[d + 1]);
    }
}

// ---------------- kernel B: 8-wave 9-diagonal propagation ----------------
__device__ __forceinline__ float blo(unsigned u) { return __uint_as_float(u << 16); }
__device__ __forceinline__ float bhi(unsigned u) { return __uint_as_float(u & 0xffff0000u); }

__device__ __forceinline__ void lds_barrier() {
    asm volatile("s_waitcnt lgkmcnt(0)" ::: "memory");
    __builtin_amdgcn_s_barrier();
}

// lane owns rows R=2*tid, R+1; weights for both rows of diagonal d = one dword
__device__ __forceinline__ void loadW(const __hip_bfloat16* __restrict__ band9,
                                      int q, int R, unsigned (&u)[9]) {
    const __hip_bfloat16* base = band9 + (size_t)q * 9 * NYP + R;
#pragma unroll
    for (int d = 0; d < 9; ++d)
        u[d] = *reinterpret_cast<const unsigned*>(base + d * NYP);
}

// hal layout: [parity][wave][0=first4rows,1=last4rows][4]
__device__ __forceinline__ void read_halo(const float (*cur)[2][4], int w,
                                          float (&hL)[4], float (&hR)[4]) {
#pragma unroll
    for (int j = 0; j < 4; ++j) {
        hL[j] = (w > 0) ? cur[w - 1][1][j] : 0.0f;   // rows 128w-4..128w-1
        hR[j] = (w < 7) ? cur[w + 1][0][j] : 0.0f;   // rows 128(w+1)..+3
    }
}

__device__ __forceinline__ void stepX(float& h0, float& h1, const unsigned (&q)[9],
                                      float (&hL)[4], float (&hR)[4],
                                      float (*nxt)[2][4], int w, int l) {
    // halo rows R-4..R-1 and R+2..R+5 via shuffles; wave-edge lanes patch from LDS
    float lh0 = __shfl_up(h0, 2),   lh1 = __shfl_up(h1, 2);    // R-4, R-3
    float lh2 = __shfl_up(h0, 1),   lh3 = __shfl_up(h1, 1);    // R-2, R-1
    float rh0 = __shfl_down(h0, 1), rh1 = __shfl_down(h1, 1);  // R+2, R+3
    float rh2 = __shfl_down(h0, 2), rh3 = __shfl_down(h1, 2);  // R+4, R+5
    if (l == 0)  { lh0 = hL[0]; lh1 = hL[1]; lh2 = hL[2]; lh3 = hL[3]; }
    if (l == 1)  { lh0 = hL[2]; lh1 = hL[3]; }
    if (l == 63) { rh0 = hR[0]; rh1 = hR[1]; rh2 = hR[2]; rh3 = hR[3]; }
    if (l == 62) { rh2 = hR[0]; rh3 = hR[1]; }

    // row R   (even -> low bf16):  cols R-4..R+4
    float n0 =            blo(q[0]) * lh0;
    n0 = fmaf(blo(q[1]), lh1, n0);
    n0 = fmaf(blo(q[2]), lh2, n0);
    n0 = fmaf(blo(q[3]), lh3, n0);
    n0 = fmaf(blo(q[4]), h0,  n0);
    n0 = fmaf(blo(q[5]), h1,  n0);
    n0 = fmaf(blo(q[6]), rh0, n0);
    n0 = fmaf(blo(q[7]), rh1, n0);
    n0 = fmaf(blo(q[8]), rh2, n0);
    // row R+1 (odd  -> high bf16): cols R-3..R+5
    float n1 =            bhi(q[0]) * lh1;
    n1 = fmaf(bhi(q[1]), lh2, n1);
    n1 = fmaf(bhi(q[2]), lh3, n1);
    n1 = fmaf(bhi(q[3]), h0,  n1);
    n1 = fmaf(bhi(q[4]), h1,  n1);
    n1 = fmaf(bhi(q[5]), rh0, n1);
    n1 = fmaf(bhi(q[6]), rh1, n1);
    n1 = fmaf(bhi(q[7]), rh2, n1);
    n1 = fmaf(bhi(q[8]), rh3, n1);
    h0 = n0; h1 = n1;

    // publish wave-edge rows for the next step (other parity buffer)
    if (l < 2)   { nxt[w][0][2 * l]        = h0; nxt[w][0][2 * l + 1]        = h1; }
    if (l >= 62) { nxt[w][1][2 * (l - 62)] = h0; nxt[w][1][2 * (l - 62) + 1] = h1; }
    lds_barrier();   // LDS-scope only; weight prefetch (vmcnt) stays in flight
    read_halo(nxt, w, hL, hR);   // issue next step's halo reads now
}

__global__ __launch_bounds__(512) void propagate9x(const float* __restrict__ x,
                                                   const __hip_bfloat16* __restrict__ band9,
                                                   float* __restrict__ out) {
    __shared__ float hal[2][8][2][4];
    const int b   = blockIdx.x;
    const int tid = threadIdx.x;
    const int w   = tid >> 6;
    const int l   = tid & 63;
    const int R   = tid << 1;   // rows R, R+1

    float h0, h1;
    {
        float2 v = *reinterpret_cast<const float2*>(x + (size_t)b * NYP + R);
        h0 = v.x; h1 = v.y;
    }

    unsigned qa[9], qb[9];
    loadW(band9, 0, R, qa);

    // prologue: publish step-0 halo into parity 0
    if (l < 2)   { hal[0][w][0][2 * l]        = h0; hal[0][w][0][2 * l + 1]        = h1; }
    if (l >= 62) { hal[0][w][1][2 * (l - 62)] = h0; hal[0][w][1][2 * (l - 62) + 1] = h1; }
    lds_barrier();
    float hL[4], hR[4];
    read_halo(hal[0], w, hL, hR);

#pragma unroll 1
    for (int s = 0; s < NQ; s += 2) {
        loadW(band9, (s + 1 < NQ) ? s + 1 : NQ - 1, R, qb);
        stepX(h0, h1, qa, hL, hR, hal[1], w, l);   // writes parity 1
        loadW(band9, (s + 2 < NQ) ? s + 2 : NQ - 1, R, qa);
        stepX(h0, h1, qb, hL, hR, hal[0], w, l);   // writes parity 0
    }

    *reinterpret_cast<float2*>(out + (size_t)b * NYP + R) = make_float2(h0, h1);
}

// ---------------- fallback: direct tridiag sweep from W (ws too small) ----------------
__device__ __forceinline__ float gAw(const float* __restrict__ Wl, int r) {
    return (r >= 1 && r < NYP) ? Wl[(size_t)r * NYP + (r - 1)] : 0.0f;
}
__device__ __forceinline__ float gBw(const float* __restrict__ Wl, int r) {
    return ((unsigned)r < NYP) ? Wl[(size_t)r * NYP + r] : 0.0f;
}
__device__ __forceinline__ float gCw(const float* __restrict__ Wl, int r) {
    return (r >= 0 && r < NYP - 1) ? Wl[(size_t)r * NYP + (r + 1)] : 0.0f;
}

__global__ __launch_bounds__(64) void propagate_direct(const float* __restrict__ x,
                                                       const float* __restrict__ W,
                                                       float* __restrict__ out) {
    const int b    = blockIdx.x;
    const int lane = threadIdx.x & 63;
    const int r0   = lane * 16;

    float h[16];
    const float4* xb = reinterpret_cast<const float4*>(x + (size_t)b * NYP + r0);
#pragma unroll
    for (int t = 0; t < 4; ++t) {
        float4 v = xb[t];
        h[4 * t + 0] = v.x; h[4 * t + 1] = v.y;
        h[4 * t + 2] = v.z; h[4 * t + 3] = v.w;
    }

#pragma unroll 1
    for (int ll = 0; ll < NXL; ++ll) {
        const float* Wl = W + ((size_t)ll << 20);
        float a[16], bb[16], c[16];
#pragma unroll
        for (int k = 0; k < 16; ++k) {
            int i = r0 + k;
            a[k] = gAw(Wl, i); bb[k] = gBw(Wl, i); c[k] = gCw(Wl, i);
        }
        float left  = __shfl_up(h[15], 1);
        float right = __shfl_down(h[0], 1);
        float carry = left;
        float n[16];
#pragma unroll
        for (int j = 0; j < 16; ++j) {
            float hp = (j == 15) ? right : h[j + 1];
            n[j] = fmaf(a[j], carry, fmaf(bb[j], h[j], c[j] * hp));
            carry = h[j];
        }
#pragma unroll
        for (int j = 0; j < 16; ++j) h[j] = n[j];
    }

    float4* ob = reinterpret_cast<float4*>(out + (size_t)b * NYP + r0);
#pragma unroll
    for (int t = 0; t < 4; ++t)
        ob[t] = make_float4(h[4 * t + 0], h[4 * t + 1], h[4 * t + 2], h[4 * t + 3]);
}

extern "C" void kernel_launch(void* const* d_in, const int* in_sizes, int n_in,
                              void* d_out, int out_size, void* d_ws, size_t ws_size,
                              hipStream_t stream) {
    const float* x = (const float*)d_in[0];   // [256,1024] f32
    const float* W = (const float*)d_in[1];   // [128,1024,1024] f32
    float* out = (float*)d_out;               // [256,1024] f32

    const size_t band9Bytes = (size_t)NQ * 9 * NYP * sizeof(__hip_bfloat16);  // 576 KB
    if (ws_size >= band9Bytes) {
        __hip_bfloat16* band9 = (__hip_bfloat16*)d_ws;
        gather_compose<<<NQ * 8, 256, 0, stream>>>(W, band9);
        propagate9x<<<NB, 512, 0, stream>>>(x, band9, out);
    } else {
        propagate_direct<<<NB, 64, 0, stream>>>(x, W, out);
    }
}